// Round 4
// baseline (894.622 us; speedup 1.0000x reference)
//
#include <hip/hip_runtime.h>
#include <math.h>

// Problem constants (B=2, T=512 -> N=1024 tokens)
constexpr int N    = 1024;
constexpr int DIM  = 512;
constexpr int HID  = 2048;
constexpr int NE   = 64;

__device__ inline void fma4(float4& a, float s, const float4& w) {
    a.x = fmaf(s, w.x, a.x);
    a.y = fmaf(s, w.y, a.y);
    a.z = fmaf(s, w.z, a.z);
    a.w = fmaf(s, w.w, a.w);
}

// ---------------------------------------------------------------------------
// Gating: logits = (x @ emb^T)/sqrt(din); softmax; gate=max prob; idx=argmax.
// f64 accumulation so argmax matches the true argmax. 4 tokens per block.
// ---------------------------------------------------------------------------
template <int DIN>
__global__ __launch_bounds__(256) void gating_kernel(
    const float* __restrict__ X, const float* __restrict__ emb,
    float* __restrict__ gate, int* __restrict__ idx, int* __restrict__ cnt)
{
    constexpr int TPB = 4;
    const int n0  = blockIdx.x * TPB;
    const int tid = threadIdx.x;

    __shared__ float  xs[TPB][DIN];
    __shared__ double red[256];

    for (int i = tid; i < TPB * (DIN / 4); i += 256) {
        const int tk = i / (DIN / 4), j = i % (DIN / 4);
        ((float4*)xs[tk])[j] = ((const float4*)(X + (size_t)(n0 + tk) * DIN))[j];
    }
    __syncthreads();

    const int e    = tid >> 2;
    const int part = tid & 3;
    constexpr int SEG = DIN / 4;

    const float4* w4 = (const float4*)(emb + (size_t)e * DIN + part * SEG);
    double acc[TPB] = {0.0, 0.0, 0.0, 0.0};

    for (int i = 0; i < SEG / 4; i++) {
        const float4 wv = w4[i];
        #pragma unroll
        for (int tk = 0; tk < TPB; tk++) {
            const float4 xv = ((const float4*)(xs[tk] + part * SEG))[i];
            acc[tk] += (double)xv.x * (double)wv.x + (double)xv.y * (double)wv.y
                     + (double)xv.z * (double)wv.z + (double)xv.w * (double)wv.w;
        }
    }

    for (int tk = 0; tk < TPB; tk++) {
        red[tid] = acc[tk];
        __syncthreads();
        if (tid < 64) {  // wave 0
            double s = red[tid * 4] + red[tid * 4 + 1] + red[tid * 4 + 2] + red[tid * 4 + 3];
            float  l = (float)(s / sqrt((double)DIN));

            float m = l; int mi = tid;
            #pragma unroll
            for (int off = 32; off > 0; off >>= 1) {
                float om = __shfl_down(m, off);
                int   oi = __shfl_down(mi, off);
                if (om > m || (om == m && oi < mi)) { m = om; mi = oi; }
            }
            m  = __shfl(m, 0);
            mi = __shfl(mi, 0);

            float p = expf(l - m);
            float ss = p;
            #pragma unroll
            for (int off = 32; off > 0; off >>= 1) ss += __shfl_down(ss, off);

            if (tid == 0) {
                gate[n0 + tk] = 1.0f / ss;
                idx[n0 + tk]  = mi;
                atomicAdd(&cnt[mi], 1);
            }
        }
        __syncthreads();
    }
}

// ---------------------------------------------------------------------------
// Fused exclusive-scan + ranked scatter. One block, N threads.
// ---------------------------------------------------------------------------
__global__ __launch_bounds__(1024) void scan_scatter(
    const int* __restrict__ cnt, const int* __restrict__ idx,
    int* __restrict__ off, int* __restrict__ bucket)
{
    __shared__ int soff[NE];
    __shared__ int scur[NE];
    const int tid = threadIdx.x;

    if (tid == 0) {
        int s = 0;
        for (int e = 0; e < NE; e++) { soff[e] = s; off[e] = s; s += cnt[e]; }
    }
    if (tid < NE) scur[tid] = 0;
    __syncthreads();

    const int e = idx[tid];
    const int p = atomicAdd(&scur[e], 1);
    bucket[soff[e] + p] = tid;
}

// ---------------------------------------------------------------------------
// Grouped GEMM layer 1 + gate scale + exact GELU.
// grid = (NE, 16 col-blocks of 128) -> 1024 blocks -> 4 blocks/CU (32 KB LDS).
// Lane map: q = l&31 (col quad), rp = l>>5 (K-row parity). Wave = token octet.
// xs is DE-INTERLEAVED by parity: xs[t][rp][d] = x[t][kc*256 + 2d + rp], so a
// lane reads its 4 consecutive K-steps as ONE ds_read_b128 (broadcast/2-way,
// conflict-free) instead of 4 scalar ds_read_b32 -> 4x fewer LDS instrs.
// W prefetch: branchless depth-8 (two 4-row banks, min-clamped reload addr)
// -> 8 KB/wave in flight, scheduler-hoistable. No atomics; shfl_xor(32)
// reduces the 2 parities; W1 read exactly once grid-wide.
// ---------------------------------------------------------------------------
__global__ __launch_bounds__(256, 4) void moe_gemm1(
    const float* __restrict__ X,  const float* __restrict__ W1,
    const float* __restrict__ b1, const float* __restrict__ gate,
    const int* __restrict__ cnt,  const int* __restrict__ off,
    const int* __restrict__ bucket, float* __restrict__ H)
{
    const int e    = blockIdx.x;
    const int mt   = cnt[e];
    if (mt == 0) return;
    const int base = off[e];
    const int cb   = blockIdx.y;
    const int tid  = threadIdx.x;
    const int wv   = tid >> 6;          // wave -> token octet
    const int l    = tid & 63;
    const int q    = l & 31;            // col quad
    const int rp   = l >> 5;            // K-row parity (0/1)

    __shared__ float xs[32][2][128];    // 32 KB, parity-deinterleaved

    const int cq = cb * 128 + q * 4;
    const float* Wb = W1 + (size_t)e * DIM * HID + cq;
    const float4 bias4 = *(const float4*)(b1 + (size_t)e * HID + cq);

    for (int chunk = 0; chunk < mt; chunk += 32) {
        const int m = min(32, mt - chunk);

        float4 acc[8];
        #pragma unroll
        for (int t = 0; t < 8; t++) acc[t] = make_float4(0.f, 0.f, 0.f, 0.f);

        for (int kc = 0; kc < 2; kc++) {
            // stage 32 tokens x 256 K, de-interleaving parities
            for (int i = tid; i < m * 64; i += 256) {
                const int t = i >> 6, j = i & 63;
                const float4 v =
                    ((const float4*)(X + (size_t)bucket[base + chunk + t] * DIM + kc * 256))[j];
                *(float2*)&xs[t][0][j * 2] = make_float2(v.x, v.z);
                *(float2*)&xs[t][1][j * 2] = make_float2(v.y, v.w);
            }
            __syncthreads();

            // K rows this kc for this lane: kc*256 + (4g+i)*2 + rp, g=0..31
            const float* Wk = Wb + (size_t)(kc * 256 + rp) * HID;
            float4 wA[4], wB[4];
            #pragma unroll
            for (int r = 0; r < 4; r++)
                wA[r] = *(const float4*)(Wk + (size_t)(0 * 4 + r) * 2 * HID);
            #pragma unroll
            for (int r = 0; r < 4; r++)
                wB[r] = *(const float4*)(Wk + (size_t)(1 * 4 + r) * 2 * HID);

            for (int g = 0; g < 32; g += 2) {
                #pragma unroll
                for (int t = 0; t < 8; t++) {
                    const float4 xv = *(const float4*)&xs[wv * 8 + t][rp][g * 4];
                    fma4(acc[t], xv.x, wA[0]);
                    fma4(acc[t], xv.y, wA[1]);
                    fma4(acc[t], xv.z, wA[2]);
                    fma4(acc[t], xv.w, wA[3]);
                }
                {   // branchless reload: clamp -> always issued, hoistable
                    const int gn = min(g + 2, 31);
                    const float* wq = Wk + (size_t)gn * 8 * HID;
                    #pragma unroll
                    for (int r = 0; r < 4; r++)
                        wA[r] = *(const float4*)(wq + (size_t)r * 2 * HID);
                }
                #pragma unroll
                for (int t = 0; t < 8; t++) {
                    const float4 xv = *(const float4*)&xs[wv * 8 + t][rp][(g + 1) * 4];
                    fma4(acc[t], xv.x, wB[0]);
                    fma4(acc[t], xv.y, wB[1]);
                    fma4(acc[t], xv.z, wB[2]);
                    fma4(acc[t], xv.w, wB[3]);
                }
                {
                    const int gn = min(g + 3, 31);
                    const float* wq = Wk + (size_t)gn * 8 * HID;
                    #pragma unroll
                    for (int r = 0; r < 4; r++)
                        wB[r] = *(const float4*)(wq + (size_t)r * 2 * HID);
                }
            }
            __syncthreads();
        }

        // reduce the two K-row parities (lanes l and l^32)
        #pragma unroll
        for (int t = 0; t < 8; t++) {
            acc[t].x += __shfl_xor(acc[t].x, 32);
            acc[t].y += __shfl_xor(acc[t].y, 32);
            acc[t].z += __shfl_xor(acc[t].z, 32);
            acc[t].w += __shfl_xor(acc[t].w, 32);
        }

        if (rp == 0) {
            #pragma unroll
            for (int t = 0; t < 8; t++) {
                const int ti = chunk + wv * 8 + t;
                if (ti < mt) {
                    const int   tok = bucket[base + ti];
                    const float g   = gate[tok];
                    float4 v;
                    v.x = g * (acc[t].x + bias4.x);
                    v.y = g * (acc[t].y + bias4.y);
                    v.z = g * (acc[t].z + bias4.z);
                    v.w = g * (acc[t].w + bias4.w);
                    v.x = 0.5f * v.x * (1.0f + erff(v.x * 0.70710678118654752f));
                    v.y = 0.5f * v.y * (1.0f + erff(v.y * 0.70710678118654752f));
                    v.z = 0.5f * v.z * (1.0f + erff(v.z * 0.70710678118654752f));
                    v.w = 0.5f * v.w * (1.0f + erff(v.w * 0.70710678118654752f));
                    *(float4*)(H + (size_t)tok * HID + cq) = v;
                }
            }
        }
    }
}

// ---------------------------------------------------------------------------
// Grouped GEMM layer 2 + gate scale. grid = (NE, 16 col-blocks of 32) ->
// 1024 blocks -> 4 blocks/CU. Lane map: q = l&7 (col quad), p = l>>3
// (K-row phase 0..7). xs de-interleaved by phase with +4 padding
// (xs[t][8][36]): phase-p b128 reads hit 8 DISJOINT bank quads
// (4p+4g mod 32) -> conflict-free; unpadded [8][32] would be 8-way.
// Branchless depth-8 W prefetch as in gemm1. Full K=2048 in registers over
// 8 LDS chunks; epilogue = 3 shfl_xor rounds + one plain float4 store.
// ---------------------------------------------------------------------------
__global__ __launch_bounds__(256, 4) void moe_gemm2(
    const float* __restrict__ Hm, const float* __restrict__ W2,
    const float* __restrict__ b2, const float* __restrict__ gate,
    const int* __restrict__ cnt,  const int* __restrict__ off,
    const int* __restrict__ bucket, float* __restrict__ out)
{
    const int e    = blockIdx.x;
    const int mt   = cnt[e];
    if (mt == 0) return;
    const int base = off[e];
    const int cb   = blockIdx.y;
    const int tid  = threadIdx.x;
    const int wv   = tid >> 6;          // wave -> token octet
    const int l    = tid & 63;
    const int q    = l & 7;             // col quad (8 quads = 32 cols)
    const int p    = l >> 3;            // K-row phase (0..7)

    __shared__ float xs[32][8][36];     // 36 KB, phase-deinterleaved + pad

    const int cq = cb * 32 + q * 4;
    const float* Wb = W2 + (size_t)e * HID * DIM + cq;
    const float4 bias4 = *(const float4*)(b2 + (size_t)e * DIM + cq);

    for (int chunk = 0; chunk < mt; chunk += 32) {
        const int m = min(32, mt - chunk);

        float4 acc[8];
        #pragma unroll
        for (int t = 0; t < 8; t++) acc[t] = make_float4(0.f, 0.f, 0.f, 0.f);

        for (int kc = 0; kc < 8; kc++) {
            // stage 32 tokens x 256 K, de-interleaving the 8 phases
            for (int i = tid; i < m * 64; i += 256) {
                const int t = i >> 6, j = i & 63;
                const float4 v =
                    ((const float4*)(Hm + (size_t)bucket[base + chunk + t] * HID + kc * 256))[j];
                const int d = j >> 1, pb = (j & 1) * 4;
                xs[t][pb + 0][d] = v.x;
                xs[t][pb + 1][d] = v.y;
                xs[t][pb + 2][d] = v.z;
                xs[t][pb + 3][d] = v.w;
            }
            __syncthreads();

            // K rows this kc for this lane: kc*256 + (4g+i)*8 + p, g=0..7
            const float* Wk = Wb + (size_t)(kc * 256 + p) * DIM;
            float4 wA[4], wB[4];
            #pragma unroll
            for (int r = 0; r < 4; r++)
                wA[r] = *(const float4*)(Wk + (size_t)(0 * 4 + r) * 8 * DIM);
            #pragma unroll
            for (int r = 0; r < 4; r++)
                wB[r] = *(const float4*)(Wk + (size_t)(1 * 4 + r) * 8 * DIM);

            for (int g = 0; g < 8; g += 2) {
                #pragma unroll
                for (int t = 0; t < 8; t++) {
                    const float4 xv = *(const float4*)&xs[wv * 8 + t][p][g * 4];
                    fma4(acc[t], xv.x, wA[0]);
                    fma4(acc[t], xv.y, wA[1]);
                    fma4(acc[t], xv.z, wA[2]);
                    fma4(acc[t], xv.w, wA[3]);
                }
                {
                    const int gn = min(g + 2, 7);
                    const float* wq = Wk + (size_t)gn * 32 * DIM;
                    #pragma unroll
                    for (int r = 0; r < 4; r++)
                        wA[r] = *(const float4*)(wq + (size_t)r * 8 * DIM);
                }
                #pragma unroll
                for (int t = 0; t < 8; t++) {
                    const float4 xv = *(const float4*)&xs[wv * 8 + t][p][(g + 1) * 4];
                    fma4(acc[t], xv.x, wB[0]);
                    fma4(acc[t], xv.y, wB[1]);
                    fma4(acc[t], xv.z, wB[2]);
                    fma4(acc[t], xv.w, wB[3]);
                }
                {
                    const int gn = min(g + 3, 7);
                    const float* wq = Wk + (size_t)gn * 32 * DIM;
                    #pragma unroll
                    for (int r = 0; r < 4; r++)
                        wB[r] = *(const float4*)(wq + (size_t)r * 8 * DIM);
                }
            }
            __syncthreads();
        }

        // reduce the 8 K-row phases (xor 8, 16, 32 within the wave)
        #pragma unroll
        for (int t = 0; t < 8; t++) {
            #pragma unroll
            for (int mk = 8; mk <= 32; mk <<= 1) {
                acc[t].x += __shfl_xor(acc[t].x, mk);
                acc[t].y += __shfl_xor(acc[t].y, mk);
                acc[t].z += __shfl_xor(acc[t].z, mk);
                acc[t].w += __shfl_xor(acc[t].w, mk);
            }
        }

        if (p == 0) {
            #pragma unroll
            for (int t = 0; t < 8; t++) {
                const int ti = chunk + wv * 8 + t;
                if (ti < mt) {
                    const int   tok = bucket[base + ti];
                    const float g   = gate[tok];
                    float4 v;
                    v.x = g * (acc[t].x + bias4.x);
                    v.y = g * (acc[t].y + bias4.y);
                    v.z = g * (acc[t].z + bias4.z);
                    v.w = g * (acc[t].w + bias4.w);
                    *(float4*)(out + (size_t)tok * DIM + cq) = v;
                }
            }
        }
    }
}

// ---------------------------------------------------------------------------
extern "C" void kernel_launch(void* const* d_in, const int* in_sizes, int n_in,
                              void* d_out, int out_size, void* d_ws, size_t ws_size,
                              hipStream_t stream)
{
    const float* x    = (const float*)d_in[0];
    const float* emb1 = (const float*)d_in[1];
    const float* W1   = (const float*)d_in[2];
    const float* b1   = (const float*)d_in[3];
    const float* emb2 = (const float*)d_in[4];
    const float* W2   = (const float*)d_in[5];
    const float* b2   = (const float*)d_in[6];
    float* out = (float*)d_out;

    // workspace layout (~8.03 MB)
    float* H       = (float*)d_ws;              // N*HID
    float* gate1   = H + (size_t)N * HID;       // N
    float* gate2   = gate1 + N;                 // N
    int*   idx1    = (int*)(gate2 + N);         // N
    int*   idx2    = idx1 + N;                  // N
    int*   bucket1 = idx2 + N;                  // N
    int*   bucket2 = bucket1 + N;               // N
    int*   cnt1    = bucket2 + N;               // 4*NE contiguous ints below
    int*   off1    = cnt1 + NE;
    int*   cnt2    = off1 + NE;
    int*   off2    = cnt2 + NE;

    hipMemsetAsync(cnt1, 0, 4 * NE * sizeof(int), stream);

    // layer 1
    gating_kernel<DIM><<<N / 4, 256, 0, stream>>>(x, emb1, gate1, idx1, cnt1);
    scan_scatter<<<1, N, 0, stream>>>(cnt1, idx1, off1, bucket1);
    moe_gemm1<<<dim3(NE, 16), 256, 0, stream>>>(x, W1, b1, gate1, cnt1, off1,
                                                bucket1, H);
    // layer 2
    gating_kernel<HID><<<N / 4, 256, 0, stream>>>(H, emb2, gate2, idx2, cnt2);
    scan_scatter<<<1, N, 0, stream>>>(cnt2, idx2, off2, bucket2);
    moe_gemm2<<<dim3(NE, 16), 256, 0, stream>>>(H, W2, b2, gate2, cnt2, off2,
                                                bucket2, out);
}